// Round 4
// baseline (1571.384 us; speedup 1.0000x reference)
//
#include <hip/hip_runtime.h>
#include <cstddef>

#define BB   4
#define PP   4096      // 64*64
#define CIN  1792
#define CWD  1794      // CIN + 2 coord channels
#define NCO  448
#define KK   4096

typedef __attribute__((ext_vector_type(8))) short short8;
typedef __attribute__((ext_vector_type(4))) float f32x4;
typedef unsigned short u16;

static __device__ __forceinline__ u16 f2bf(float f) {
    unsigned int u = __float_as_uint(f);
    u += 0x7fffu + ((u >> 16) & 1u);    // round-to-nearest-even
    return (u16)(u >> 16);
}
static __device__ __forceinline__ float bf2f(u16 s) {
    return __uint_as_float(((unsigned int)s) << 16);
}

// ---------------- 3x3 avg pool, stride 1, pad 1, count_include_pad (sum/9) ----------------
__global__ void pool3_kernel(const float* __restrict__ in, float* __restrict__ out, int S) {
    int plane = blockIdx.y;
    int idx = blockIdx.x * 256 + threadIdx.x;
    if (idx >= S * S) return;
    int h = idx / S, w = idx % S;
    const float* p = in + (size_t)plane * S * S;
    float s = 0.f;
    for (int dh = -1; dh <= 1; ++dh) {
        int hh = h + dh;
        if (hh < 0 || hh >= S) continue;
        for (int dw = -1; dw <= 1; ++dw) {
            int ww = w + dw;
            if (ww < 0 || ww >= S) continue;
            s += p[hh * S + ww];
        }
    }
    out[(size_t)plane * S * S + idx] = s * (1.f / 9.f);
}

// ---------------- W[o][c] -> Wt[c][o] ----------------
__global__ void wt_kernel(const float* __restrict__ W, float* __restrict__ Wt) {
    int i = blockIdx.x * 256 + threadIdx.x;
    if (i >= CWD * NCO) return;
    int c = i / NCO, o = i % NCO;
    Wt[i] = W[(size_t)o * CWD + c];
}

// ---------------- mb prep (deterministic, no atomics): mbT_h/l[k][c] + ||mb[:,k]||^2 ----------
__global__ void mb_prep_kernel(const float* __restrict__ mb, u16* __restrict__ mbTh,
                               u16* __restrict__ mbTl, float* __restrict__ mbn) {
    int k = blockIdx.x * 256 + threadIdx.x;   // 16 blocks x 256 = 4096
    float s = 0.f;
    for (int c = 0; c < NCO; ++c) {
        float v = mb[(size_t)c * KK + k];      // coalesced along k
        s += v * v;
        u16 h = f2bf(v);
        mbTh[(size_t)k * NCO + c] = h;
        mbTl[(size_t)k * NCO + c] = f2bf(v - bf2f(h));
    }
    mbn[k] = s;
}

// ---------------- t fp32 -> th/tl bf16 split (same [row][c] layout) ----------------
__global__ void split_t_kernel(const float* __restrict__ t, u16* __restrict__ th,
                               u16* __restrict__ tl) {
    size_t i = (size_t)blockIdx.x * 256 + threadIdx.x;   // float4 index
    float4 v = ((const float4*)t)[i];
    ushort4 h, l;
    h.x = f2bf(v.x); l.x = f2bf(v.x - bf2f(h.x));
    h.y = f2bf(v.y); l.y = f2bf(v.y - bf2f(h.y));
    h.z = f2bf(v.z); l.z = f2bf(v.z - bf2f(h.z));
    h.w = f2bf(v.w); l.w = f2bf(v.w - bf2f(h.w));
    ((ushort4*)th)[i] = h;
    ((ushort4*)tl)[i] = l;
}

// ---------------- descriptor: t[b][p][o] = sum_c feat[b,c,p] * W[o,c] + coords + bias ----------
// grid (7 o-tiles, 64 rows, B). block 256: 64 p x 64 o tile, fused multiscale bilinear gather.
__global__ __launch_bounds__(256) void desc_kernel(
    const float* __restrict__ p1v, const float* __restrict__ p2v,
    const float* __restrict__ p3v, const float* __restrict__ Wt,
    const float* __restrict__ bias, float* __restrict__ t)
{
    __shared__ __align__(16) float A[64][64];
    __shared__ __align__(16) float Wl[64][64];

    int bz = blockIdx.z;
    int p0 = blockIdx.y * 64;
    int o0 = blockIdx.x * 64;
    int tid = threadIdx.x;
    int lane = tid & 63, grp = tid >> 6;

    int h = p0 >> 6;     // block covers one image row
    int w = lane;

    // bilinear, half-pixel centers, clamp (== jax.image.resize edge renorm)
    float s2h = 0.5f * h - 0.25f;  int h2a = (int)floorf(s2h); float f2h = s2h - h2a;
    int h2b = min(max(h2a + 1, 0), 31); h2a = min(max(h2a, 0), 31);
    float s2w = 0.5f * w - 0.25f;  int w2a = (int)floorf(s2w); float f2w = s2w - w2a;
    int w2b = min(max(w2a + 1, 0), 31); w2a = min(max(w2a, 0), 31);
    float s4h = 0.25f * h - 0.375f; int h4a = (int)floorf(s4h); float f4h = s4h - h4a;
    int h4b = min(max(h4a + 1, 0), 15); h4a = min(max(h4a, 0), 15);
    float s4w = 0.25f * w - 0.375f; int w4a = (int)floorf(s4w); float f4w = s4w - w4a;
    int w4b = min(max(w4a + 1, 0), 15); w4a = min(max(w4a, 0), 15);

    int tx = tid & 15, ty = tid >> 4;
    float acc[4][4] = {};

    for (int c0 = 0; c0 < CIN; c0 += 64) {
        __syncthreads();
        #pragma unroll
        for (int i = 0; i < 16; ++i) {
            int cl = grp + 4 * i;
            Wl[cl][lane] = Wt[(size_t)(c0 + cl) * NCO + o0 + lane];
        }
        #pragma unroll 2
        for (int i = 0; i < 16; ++i) {
            int cl = grp + 4 * i;
            int c = c0 + cl;
            float v;
            if (c < 256) {
                v = p1v[(((size_t)bz * 256 + c) * 64 + h) * 64 + w];
            } else if (c < 768) {
                const float* q = p2v + ((size_t)bz * 512 + (c - 256)) * 1024;
                float va = q[h2a * 32 + w2a], vb = q[h2a * 32 + w2b];
                float vc = q[h2b * 32 + w2a], vd = q[h2b * 32 + w2b];
                v = (1.f - f2h) * ((1.f - f2w) * va + f2w * vb)
                  +        f2h  * ((1.f - f2w) * vc + f2w * vd);
            } else {
                const float* q = p3v + ((size_t)bz * 1024 + (c - 768)) * 256;
                float va = q[h4a * 16 + w4a], vb = q[h4a * 16 + w4b];
                float vc = q[h4b * 16 + w4a], vd = q[h4b * 16 + w4b];
                v = (1.f - f4h) * ((1.f - f4w) * va + f4w * vb)
                  +        f4h  * ((1.f - f4w) * vc + f4w * vd);
            }
            A[cl][lane] = v;
        }
        __syncthreads();
        #pragma unroll 8
        for (int c = 0; c < 64; ++c) {
            float4 a4 = *(const float4*)&A[c][tx * 4];
            float4 w4 = *(const float4*)&Wl[c][ty * 4];
            float av[4] = {a4.x, a4.y, a4.z, a4.w};
            float wv[4] = {w4.x, w4.y, w4.z, w4.w};
            #pragma unroll
            for (int i = 0; i < 4; ++i)
                #pragma unroll
                for (int j = 0; j < 4; ++j)
                    acc[i][j] = fmaf(av[i], wv[j], acc[i][j]);
        }
    }

    float xx = (float)h * (2.f / 63.f) - 1.f;
    int o = o0 + ty * 4;
    float wx0 = Wt[(size_t)1792 * NCO + o + 0], wx1 = Wt[(size_t)1792 * NCO + o + 1];
    float wx2 = Wt[(size_t)1792 * NCO + o + 2], wx3 = Wt[(size_t)1792 * NCO + o + 3];
    float wy0 = Wt[(size_t)1793 * NCO + o + 0], wy1 = Wt[(size_t)1793 * NCO + o + 1];
    float wy2 = Wt[(size_t)1793 * NCO + o + 2], wy3 = Wt[(size_t)1793 * NCO + o + 3];
    float b0 = bias[o + 0], b1 = bias[o + 1], b2 = bias[o + 2], b3 = bias[o + 3];
    #pragma unroll
    for (int i = 0; i < 4; ++i) {
        int p = p0 + tx * 4 + i;
        float yy = (float)(p & 63) * (2.f / 63.f) - 1.f;
        float4 r;
        r.x = acc[i][0] + b0 + xx * wx0 + yy * wy0;
        r.y = acc[i][1] + b1 + xx * wx1 + yy * wy1;
        r.z = acc[i][2] + b2 + xx * wx2 + yy * wy2;
        r.w = acc[i][3] + b3 + xx * wx3 + yy * wy3;
        *(float4*)&t[((size_t)bz * PP + p) * NCO + o] = r;
    }
}

// ---------------- ||t[row]||^2, one wave per row ----------------
__global__ void tnorm_kernel(const float* __restrict__ t, float* __restrict__ tn) {
    int row = blockIdx.x * 4 + (threadIdx.x >> 6);
    int lane = threadIdx.x & 63;
    const float* tr = t + (size_t)row * NCO;
    float s = 0.f;
    for (int c = lane; c < NCO; c += 64) {
        float v = tr[c];
        s += v * v;
    }
    for (int off = 32; off > 0; off >>= 1) s += __shfl_down(s, off);
    if (lane == 0) tn[row] = s;
}

// ---------------- distance via split-bf16 MFMA + top-3 + softmin score ----------------
// Block: 64 t-rows, 8 waves (4m x 2n). t hi/lo staged in LDS once; mbT streamed from L2/LLC.
// mfma_f32_16x16x32_bf16 operand map: A[m][k] m=lane&15, k=(lane>>4)*8+e (e contiguous);
// B[k][n] n=lane&15, same k; D[m][n] n=lane&15, m=(lane>>4)*4+reg  [m89-verified C/D].
// acc = th*mh + th*ml + tl*mh  (lo*lo dropped: ~5e-4 abs in d^2 ~ 770; fp32 accum).
__global__ __launch_bounds__(512) void dist_mfma_kernel(
    const u16* __restrict__ th, const u16* __restrict__ tl,
    const u16* __restrict__ mbTh, const u16* __restrict__ mbTl,
    const float* __restrict__ tn, const float* __restrict__ mbn,
    float* __restrict__ out)
{
    __shared__ __align__(16) u16 ThL[64][456];   // +8 pad; 138 KB total LDS (1 block/CU)
    __shared__ __align__(16) u16 TlL[64][456];
    __shared__ float TOPS[64][32][3];

    int tid = threadIdx.x;
    int r0 = blockIdx.x * 64;

    // stage 64 rows x 448 of th/tl: 3584 16B-chunks each, 7 per thread
    #pragma unroll
    for (int it = 0; it < 7; ++it) {
        int idx = tid + 512 * it;
        int row = idx / 56, c8 = (idx % 56) * 8;
        *(short8*)&ThL[row][c8] = *(const short8*)&th[(size_t)(r0 + row) * NCO + c8];
        *(short8*)&TlL[row][c8] = *(const short8*)&tl[(size_t)(r0 + row) * NCO + c8];
    }

    int lane = tid & 63, wave = tid >> 6;
    int wm = wave >> 1, wn = wave & 1;
    int l15 = lane & 15, l4 = lane >> 4;

    float tnr[4];
    #pragma unroll
    for (int r = 0; r < 4; ++r) tnr[r] = tn[r0 + wm * 16 + l4 * 4 + r];

    float top0[4], top1[4], top2[4];
    #pragma unroll
    for (int r = 0; r < 4; ++r) { top0[r] = 3.4e38f; top1[r] = 3.4e38f; top2[r] = 3.4e38f; }

    __syncthreads();

    const int arow = wm * 16 + l15;
    const int acol = l4 * 8;

    for (int k0 = 0; k0 < KK; k0 += 128) {
        f32x4 acc[4];
        #pragma unroll
        for (int nt = 0; nt < 4; ++nt) acc[nt] = (f32x4){0.f, 0.f, 0.f, 0.f};

        for (int cs = 0; cs < 14; ++cs) {
            short8 ah = *(const short8*)&ThL[arow][cs * 32 + acol];
            short8 al = *(const short8*)&TlL[arow][cs * 32 + acol];
            #pragma unroll
            for (int nt = 0; nt < 4; ++nt) {
                size_t boff = (size_t)(k0 + wn * 64 + nt * 16 + l15) * NCO + cs * 32 + acol;
                short8 bh = *(const short8*)&mbTh[boff];
                short8 bl = *(const short8*)&mbTl[boff];
                acc[nt] = __builtin_amdgcn_mfma_f32_16x16x32_bf16(ah, bh, acc[nt], 0, 0, 0);
                acc[nt] = __builtin_amdgcn_mfma_f32_16x16x32_bf16(ah, bl, acc[nt], 0, 0, 0);
                acc[nt] = __builtin_amdgcn_mfma_f32_16x16x32_bf16(al, bh, acc[nt], 0, 0, 0);
            }
        }
        #pragma unroll
        for (int nt = 0; nt < 4; ++nt) {
            float nb = mbn[k0 + wn * 64 + nt * 16 + l15];
            #pragma unroll
            for (int r = 0; r < 4; ++r) {
                float d2 = tnr[r] + nb - 2.f * acc[nt][r];
                if (d2 < top0[r])      { top2[r] = top1[r]; top1[r] = top0[r]; top0[r] = d2; }
                else if (d2 < top1[r]) { top2[r] = top1[r]; top1[r] = d2; }
                else if (d2 < top2[r]) { top2[r] = d2; }
            }
        }
    }

    #pragma unroll
    for (int r = 0; r < 4; ++r) {
        int rr = wm * 16 + l4 * 4 + r;
        TOPS[rr][wn * 16 + l15][0] = top0[r];
        TOPS[rr][wn * 16 + l15][1] = top1[r];
        TOPS[rr][wn * 16 + l15][2] = top2[r];
    }
    __syncthreads();

    if (tid < 64) {
        float a0 = 3.4e38f, a1 = 3.4e38f, a2 = 3.4e38f;
        for (int q = 0; q < 32; ++q) {
            #pragma unroll
            for (int e = 0; e < 3; ++e) {
                float v = TOPS[tid][q][e];
                if (v < a0)      { a2 = a1; a1 = a0; a0 = v; }
                else if (v < a1) { a2 = a1; a1 = v; }
                else if (v < a2) { a2 = v; }
            }
        }
        float d1 = sqrtf(fmaxf(a0, 1e-12f));
        float d2 = sqrtf(fmaxf(a1, 1e-12f));
        float d3 = sqrtf(fmaxf(a2, 1e-12f));
        float e2 = expf(d1 - d2), e3 = expf(d1 - d3);   // both <= 1, stable
        out[r0 + tid] = d1 / (1.f + e2 + e3);
    }
}

extern "C" void kernel_launch(void* const* d_in, const int* in_sizes, int n_in,
                              void* d_out, int out_size, void* d_ws, size_t ws_size,
                              hipStream_t stream) {
    (void)in_sizes; (void)n_in; (void)out_size; (void)ws_size;
    const float* f1   = (const float*)d_in[0];
    const float* f2   = (const float*)d_in[1];
    const float* f3   = (const float*)d_in[2];
    const float* W    = (const float*)d_in[3];
    const float* bias = (const float*)d_in[4];
    const float* mb   = (const float*)d_in[5];
    float* out = (float*)d_out;

    // workspace layout: floats then bf16 regions; total ~94.2 MB, every region fully written
    float* p1  = (float*)d_ws;
    float* p2  = p1  + (size_t)BB * 256 * 64 * 64;   // 4,194,304 f
    float* p3  = p2  + (size_t)BB * 512 * 32 * 32;   // 2,097,152 f
    float* Wt  = p3  + (size_t)BB * 1024 * 16 * 16;  // 1,048,576 f
    float* t   = Wt  + (size_t)CWD * NCO;            //   803,712 f
    float* tn  = t   + (size_t)BB * PP * NCO;        // 7,340,032 f
    float* mbn = tn  + (size_t)BB * PP;              //    16,384 f
    u16* th   = (u16*)(mbn + KK);                    // 16B-aligned offset
    u16* tl   = th   + (size_t)BB * PP * NCO;        // 7,340,032 each
    u16* mbTh = tl   + (size_t)BB * PP * NCO;
    u16* mbTl = mbTh + (size_t)KK * NCO;             // 1,835,008 each

    pool3_kernel<<<dim3(16, BB * 256),  256, 0, stream>>>(f1, p1, 64);
    pool3_kernel<<<dim3(4,  BB * 512),  256, 0, stream>>>(f2, p2, 32);
    pool3_kernel<<<dim3(1,  BB * 1024), 256, 0, stream>>>(f3, p3, 16);
    wt_kernel<<<(CWD * NCO + 255) / 256, 256, 0, stream>>>(W, Wt);
    mb_prep_kernel<<<KK / 256, 256, 0, stream>>>(mb, mbTh, mbTl, mbn);
    desc_kernel<<<dim3(7, 64, BB), 256, 0, stream>>>(p1, p2, p3, Wt, bias, t);
    tnorm_kernel<<<(BB * PP) / 4, 256, 0, stream>>>(t, tn);
    split_t_kernel<<<(BB * PP * NCO / 4) / 256, 256, 0, stream>>>(t, th, tl);
    dist_mfma_kernel<<<(BB * PP) / 64, 512, 0, stream>>>(th, tl, mbTh, mbTl, tn, mbn, out);
}

// Round 7
// 1498.301 us; speedup vs baseline: 1.0488x; 1.0488x over previous
//
#include <hip/hip_runtime.h>
#include <cstddef>

#define BB   4
#define PP   4096      // 64*64
#define CWD  1794      // 1792 + 2 coord channels
#define NCO  448
#define KK   4096

typedef __attribute__((ext_vector_type(8))) short short8;
typedef __attribute__((ext_vector_type(4))) float f32x4;
typedef unsigned short u16;

static __device__ __forceinline__ u16 f2bf(float f) {
    unsigned int u = __float_as_uint(f);
    u += 0x7fffu + ((u >> 16) & 1u);    // round-to-nearest-even
    return (u16)(u >> 16);
}
static __device__ __forceinline__ float bf2f(u16 s) {
    return __uint_as_float(((unsigned int)s) << 16);
}
static __device__ __forceinline__ void ins3(float v, float& t0, float& t1, float& t2) {
    if (v < t0)      { t2 = t1; t1 = t0; t0 = v; }
    else if (v < t1) { t2 = t1; t1 = v; }
    else if (v < t2) { t2 = v; }
}

// ---------------- 3x3 avg pool, stride 1, pad 1, count_include_pad (sum/9) ----------------
__global__ void pool3_kernel(const float* __restrict__ in, float* __restrict__ out, int S) {
    int plane = blockIdx.y;
    int idx = blockIdx.x * 256 + threadIdx.x;
    if (idx >= S * S) return;
    int h = idx / S, w = idx % S;
    const float* p = in + (size_t)plane * S * S;
    float s = 0.f;
    for (int dh = -1; dh <= 1; ++dh) {
        int hh = h + dh;
        if (hh < 0 || hh >= S) continue;
        for (int dw = -1; dw <= 1; ++dw) {
            int ww = w + dw;
            if (ww < 0 || ww >= S) continue;
            s += p[hh * S + ww];
        }
    }
    out[(size_t)plane * S * S + idx] = s * (1.f / 9.f);
}

// ---------------- W[o][c] -> Wt[c][o] ----------------
__global__ void wt_kernel(const float* __restrict__ W, float* __restrict__ Wt) {
    int i = blockIdx.x * 256 + threadIdx.x;
    if (i >= CWD * NCO) return;
    int c = i / NCO, o = i % NCO;
    Wt[i] = W[(size_t)o * CWD + c];
}

// ---------------- mb prep (deterministic): mbT_h/l[k][c] bf16 split + ||mb[:,k]||^2 ----------
__global__ void mb_prep_kernel(const float* __restrict__ mb, u16* __restrict__ mbTh,
                               u16* __restrict__ mbTl, float* __restrict__ mbn) {
    int k = blockIdx.x * 256 + threadIdx.x;
    float s = 0.f;
    for (int c = 0; c < NCO; ++c) {
        float v = mb[(size_t)c * KK + k];      // coalesced along k
        s += v * v;
        u16 h = f2bf(v);
        mbTh[(size_t)k * NCO + c] = h;
        mbTl[(size_t)k * NCO + c] = f2bf(v - bf2f(h));
    }
    mbn[k] = s;
}

// ---------------- per-level contribution GEMM: g[b,pix,o] = sum_c p[b,c,pix] * Wt[c0w+c][o] ---
// No gather: A-stage reads are contiguous along pix. 64 pix x 64 o tile, K-loop over C.
__global__ __launch_bounds__(256) void lvl_gemm_kernel(
    const float* __restrict__ src, const float* __restrict__ Wt,
    float* __restrict__ g, int C, int PL, int c0w)
{
    __shared__ __align__(16) float A[64][64];
    __shared__ __align__(16) float Wl[64][64];

    int bz = blockIdx.z;
    int p0 = blockIdx.y * 64;
    int o0 = blockIdx.x * 64;
    int tid = threadIdx.x;
    int lane = tid & 63, grp = tid >> 6;
    int tx = tid & 15, ty = tid >> 4;
    float acc[4][4] = {};

    for (int c0 = 0; c0 < C; c0 += 64) {
        __syncthreads();
        #pragma unroll
        for (int i = 0; i < 16; ++i) {
            int cl = grp + 4 * i;
            Wl[cl][lane] = Wt[(size_t)(c0w + c0 + cl) * NCO + o0 + lane];
            A[cl][lane]  = src[((size_t)bz * C + c0 + cl) * PL + p0 + lane];
        }
        __syncthreads();
        #pragma unroll 8
        for (int c = 0; c < 64; ++c) {
            float4 a4 = *(const float4*)&A[c][tx * 4];
            float4 w4 = *(const float4*)&Wl[c][ty * 4];
            float av[4] = {a4.x, a4.y, a4.z, a4.w};
            float wv[4] = {w4.x, w4.y, w4.z, w4.w};
            #pragma unroll
            for (int i = 0; i < 4; ++i)
                #pragma unroll
                for (int j = 0; j < 4; ++j)
                    acc[i][j] = fmaf(av[i], wv[j], acc[i][j]);
        }
    }
    #pragma unroll
    for (int i = 0; i < 4; ++i) {
        float4 r;
        r.x = acc[i][0]; r.y = acc[i][1]; r.z = acc[i][2]; r.w = acc[i][3];
        *(float4*)&g[((size_t)bz * PL + p0 + tx * 4 + i) * NCO + o0 + ty * 4] = r;
    }
}

// ---------------- fuse: t = g1 + up2(g2) + up4(g3) + coords + bias; split bf16 + row norm -----
// One wave per output row (b,p). All bilinear params wave-uniform.
__global__ __launch_bounds__(256) void fuse_kernel(
    const float* __restrict__ g1, const float* __restrict__ g2, const float* __restrict__ g3,
    const float* __restrict__ Wt, const float* __restrict__ bias,
    u16* __restrict__ th, u16* __restrict__ tl, float* __restrict__ tn)
{
    int r = blockIdx.x * 4 + (threadIdx.x >> 6);
    int lane = threadIdx.x & 63;
    int b = r >> 12, p = r & 4095, h = p >> 6, w = p & 63;

    // bilinear, half-pixel centers, clamp (== jax.image.resize edge renorm); same as validated r4
    float s2h = 0.5f * h - 0.25f;  int h2a = (int)floorf(s2h); float f2h = s2h - h2a;
    int h2b = min(max(h2a + 1, 0), 31); h2a = min(max(h2a, 0), 31);
    float s2w = 0.5f * w - 0.25f;  int w2a = (int)floorf(s2w); float f2w = s2w - w2a;
    int w2b = min(max(w2a + 1, 0), 31); w2a = min(max(w2a, 0), 31);
    float s4h = 0.25f * h - 0.375f; int h4a = (int)floorf(s4h); float f4h = s4h - h4a;
    int h4b = min(max(h4a + 1, 0), 15); h4a = min(max(h4a, 0), 15);
    float s4w = 0.25f * w - 0.375f; int w4a = (int)floorf(s4w); float f4w = s4w - w4a;
    int w4b = min(max(w4a + 1, 0), 15); w4a = min(max(w4a, 0), 15);

    float c2aa = (1.f - f2h) * (1.f - f2w), c2ab = (1.f - f2h) * f2w;
    float c2ba = f2h * (1.f - f2w),         c2bb = f2h * f2w;
    float c4aa = (1.f - f4h) * (1.f - f4w), c4ab = (1.f - f4h) * f4w;
    float c4ba = f4h * (1.f - f4w),         c4bb = f4h * f4w;

    const float* G1 = g1 + (size_t)r * NCO;
    const float* G2 = g2 + (size_t)b * 1024 * NCO;
    const float* G3 = g3 + (size_t)b * 256 * NCO;
    size_t i2aa = (size_t)(h2a * 32 + w2a) * NCO, i2ab = (size_t)(h2a * 32 + w2b) * NCO;
    size_t i2ba = (size_t)(h2b * 32 + w2a) * NCO, i2bb = (size_t)(h2b * 32 + w2b) * NCO;
    size_t i4aa = (size_t)(h4a * 16 + w4a) * NCO, i4ab = (size_t)(h4a * 16 + w4b) * NCO;
    size_t i4ba = (size_t)(h4b * 16 + w4a) * NCO, i4bb = (size_t)(h4b * 16 + w4b) * NCO;

    float xx = (float)h * (2.f / 63.f) - 1.f;
    float yy = (float)w * (2.f / 63.f) - 1.f;

    float s = 0.f;
    #pragma unroll
    for (int j = 0; j < 7; ++j) {
        int c = lane + 64 * j;
        float v = G1[c]
            + c2aa * G2[i2aa + c] + c2ab * G2[i2ab + c]
            + c2ba * G2[i2ba + c] + c2bb * G2[i2bb + c]
            + c4aa * G3[i4aa + c] + c4ab * G3[i4ab + c]
            + c4ba * G3[i4ba + c] + c4bb * G3[i4bb + c]
            + xx * Wt[(size_t)1792 * NCO + c] + yy * Wt[(size_t)1793 * NCO + c] + bias[c];
        u16 hi = f2bf(v);
        th[(size_t)r * NCO + c] = hi;
        tl[(size_t)r * NCO + c] = f2bf(v - bf2f(hi));
        s += v * v;
    }
    #pragma unroll
    for (int off = 32; off > 0; off >>= 1) s += __shfl_down(s, off);
    if (lane == 0) tn[r] = s;
}

// ---------------- dist: 128x128 tile split-bf16 MFMA GEMM + per-block top-3 partials ---------
// 4 waves (2m x 2n), BK=64, 7 K-steps. A (t rows, hi/lo) in LDS w/ T14 async staging;
// B (mbT) direct global->reg (L2-resident). Same fragment conventions as validated round-4.
__global__ __launch_bounds__(256) void dist_kernel(
    const u16* __restrict__ th, const u16* __restrict__ tl,
    const u16* __restrict__ mbTh, const u16* __restrict__ mbTl,
    const float* __restrict__ tn, const float* __restrict__ mbn,
    float* __restrict__ part)
{
    __shared__ __align__(16) u16 Ah[128][72];   // +8 pad (stride 144B = 36 banks -> 2-way, free)
    __shared__ __align__(16) u16 Al[128][72];
    __shared__ float MRG[128][2][3];

    int bid = blockIdx.x;
    int swz = (bid & 7) * 512 + (bid >> 3);     // XCD swizzle (4096 % 8 == 0: bijective)
    int mt = swz >> 5, nt = swz & 31;
    int r0 = mt * 128, n0 = nt * 128;
    int tid = threadIdx.x;
    int lane = tid & 63, wv = tid >> 6;
    int wm = wv >> 1, wn = wv & 1;
    int l15 = lane & 15, l4 = lane >> 4;

    // staging map: 1024 16B-chunks per matrix, 4 per thread
    int srow[4], skc[4];
    #pragma unroll
    for (int it = 0; it < 4; ++it) {
        int cid = tid + 256 * it;
        srow[it] = cid >> 3;
        skc[it]  = cid & 7;
    }
    uint4 ra[4], rb[4];
    #pragma unroll
    for (int it = 0; it < 4; ++it) {   // prologue: K-step 0
        ra[it] = *(const uint4*)&th[(size_t)(r0 + srow[it]) * NCO + skc[it] * 8];
        rb[it] = *(const uint4*)&tl[(size_t)(r0 + srow[it]) * NCO + skc[it] * 8];
    }

    f32x4 acc[4][4];
    #pragma unroll
    for (int i = 0; i < 4; ++i)
        #pragma unroll
        for (int j = 0; j < 4; ++j) acc[i][j] = (f32x4){0.f, 0.f, 0.f, 0.f};

    for (int t7 = 0; t7 < 7; ++t7) {
        __syncthreads();                       // previous compute done; LDS writable
        #pragma unroll
        for (int it = 0; it < 4; ++it) {
            *(uint4*)&Ah[srow[it]][skc[it] * 8] = ra[it];
            *(uint4*)&Al[srow[it]][skc[it] * 8] = rb[it];
        }
        if (t7 < 6) {                          // T14: issue next-step loads early
            int k0 = (t7 + 1) * 64;
            #pragma unroll
            for (int it = 0; it < 4; ++it) {
                ra[it] = *(const uint4*)&th[(size_t)(r0 + srow[it]) * NCO + k0 + skc[it] * 8];
                rb[it] = *(const uint4*)&tl[(size_t)(r0 + srow[it]) * NCO + k0 + skc[it] * 8];
            }
        }
        __syncthreads();                       // LDS ready
        #pragma unroll
        for (int ks = 0; ks < 2; ++ks) {
            short8 ah[4], al[4];
            #pragma unroll
            for (int i = 0; i < 4; ++i) {
                ah[i] = *(const short8*)&Ah[wm * 64 + i * 16 + l15][ks * 32 + l4 * 8];
                al[i] = *(const short8*)&Al[wm * 64 + i * 16 + l15][ks * 32 + l4 * 8];
            }
            #pragma unroll
            for (int j = 0; j < 4; ++j) {
                size_t boff = (size_t)(n0 + wn * 64 + j * 16 + l15) * NCO
                            + t7 * 64 + ks * 32 + l4 * 8;
                short8 bh = *(const short8*)&mbTh[boff];
                short8 bl = *(const short8*)&mbTl[boff];
                #pragma unroll
                for (int i = 0; i < 4; ++i) {
                    acc[i][j] = __builtin_amdgcn_mfma_f32_16x16x32_bf16(ah[i], bh, acc[i][j], 0, 0, 0);
                    acc[i][j] = __builtin_amdgcn_mfma_f32_16x16x32_bf16(ah[i], bl, acc[i][j], 0, 0, 0);
                    acc[i][j] = __builtin_amdgcn_mfma_f32_16x16x32_bf16(al[i], bh, acc[i][j], 0, 0, 0);
                }
            }
        }
    }

    // epilogue: d2 = tn + mbn - 2*dot; per-row top-3 over this block's 128 cols
    float nbv[4];
    #pragma unroll
    for (int j = 0; j < 4; ++j) nbv[j] = mbn[n0 + wn * 64 + j * 16 + l15];

    #pragma unroll
    for (int i = 0; i < 4; ++i) {
        #pragma unroll
        for (int rr = 0; rr < 4; ++rr) {
            int mloc = wm * 64 + i * 16 + l4 * 4 + rr;
            float tv = tn[r0 + mloc];
            float t0 = 3.4e38f, t1 = 3.4e38f, t2 = 3.4e38f;
            #pragma unroll
            for (int j = 0; j < 4; ++j)
                ins3(tv + nbv[j] - 2.f * acc[i][j][rr], t0, t1, t2);
            #pragma unroll
            for (int mask = 1; mask <= 8; mask <<= 1) {   // butterfly over l15 bits
                float o0 = __shfl_xor(t0, mask);
                float o1 = __shfl_xor(t1, mask);
                float o2 = __shfl_xor(t2, mask);
                ins3(o0, t0, t1, t2); ins3(o1, t0, t1, t2); ins3(o2, t0, t1, t2);
            }
            if (l15 == 0) {
                MRG[mloc][wn][0] = t0; MRG[mloc][wn][1] = t1; MRG[mloc][wn][2] = t2;
            }
        }
    }
    __syncthreads();
    if (tid < 128) {
        float t0 = MRG[tid][0][0], t1 = MRG[tid][0][1], t2 = MRG[tid][0][2];
        ins3(MRG[tid][1][0], t0, t1, t2);
        ins3(MRG[tid][1][1], t0, t1, t2);
        ins3(MRG[tid][1][2], t0, t1, t2);
        size_t o = (size_t)(r0 + tid) * 96 + nt * 3;
        part[o] = t0; part[o + 1] = t1; part[o + 2] = t2;
    }
}

// ---------------- final merge: top-3 of 32 partial triples + softmin score ----------------
__global__ void score_kernel(const float* __restrict__ part, float* __restrict__ out) {
    int r = blockIdx.x * 4 + (threadIdx.x >> 6);
    int lane = threadIdx.x & 63;
    float t0 = 3.4e38f, t1 = 3.4e38f, t2 = 3.4e38f;
    ins3(part[(size_t)r * 96 + lane], t0, t1, t2);
    float v1 = (lane < 32) ? part[(size_t)r * 96 + 64 + lane] : 3.4e38f;
    ins3(v1, t0, t1, t2);
    #pragma unroll
    for (int mask = 1; mask <= 32; mask <<= 1) {
        float o0 = __shfl_xor(t0, mask);
        float o1 = __shfl_xor(t1, mask);
        float o2 = __shfl_xor(t2, mask);
        ins3(o0, t0, t1, t2); ins3(o1, t0, t1, t2); ins3(o2, t0, t1, t2);
    }
    if (lane == 0) {
        float d1 = sqrtf(fmaxf(t0, 1e-12f));
        float d2 = sqrtf(fmaxf(t1, 1e-12f));
        float d3 = sqrtf(fmaxf(t2, 1e-12f));
        float e2 = expf(d1 - d2), e3 = expf(d1 - d3);   // both <= 1, stable
        out[r] = d1 / (1.f + e2 + e3);
    }
}

extern "C" void kernel_launch(void* const* d_in, const int* in_sizes, int n_in,
                              void* d_out, int out_size, void* d_ws, size_t ws_size,
                              hipStream_t stream) {
    (void)in_sizes; (void)n_in; (void)out_size; (void)ws_size;
    const float* f1   = (const float*)d_in[0];
    const float* f2   = (const float*)d_in[1];
    const float* f3   = (const float*)d_in[2];
    const float* W    = (const float*)d_in[3];
    const float* bias = (const float*)d_in[4];
    const float* mb   = (const float*)d_in[5];
    float* out = (float*)d_out;

    // workspace: 94.15 MB total (identical footprint to the passing round-4 layout)
    float* p1  = (float*)d_ws;                       // 4,194,304 f
    float* p2  = p1  + (size_t)4194304;              // 2,097,152 f
    float* p3  = p2  + (size_t)2097152;              // 1,048,576 f
    float* Wt  = p3  + (size_t)1048576;              //   803,712 f
    float* g1  = Wt  + (size_t)803712;               // 7,340,032 f
    float* tn  = g1  + (size_t)7340032;              //    16,384 f
    float* mbn = tn  + (size_t)16384;                //     4,096 f
    u16* th    = (u16*)(mbn + 4096);                 // 7,340,032 u16
    u16* tl    = th   + (size_t)7340032;             // 7,340,032 u16
    u16* mbTh  = tl   + (size_t)7340032;             // 1,835,008 u16
    u16* mbTl  = mbTh + (size_t)1835008;             // 1,835,008 u16
    // aliases into dead regions (stream order guarantees safety):
    float* g2   = p1;                                // 1,835,008 f (p1 dead after L1 GEMM)
    float* part = p1 + (size_t)1835008;              // 1,572,864 f (written by dist, after fuse)
    float* g3   = p2;                                //   458,752 f (p2 dead after L2 GEMM)

    pool3_kernel<<<dim3(16, BB * 256),  256, 0, stream>>>(f1, p1, 64);
    pool3_kernel<<<dim3(4,  BB * 512),  256, 0, stream>>>(f2, p2, 32);
    pool3_kernel<<<dim3(1,  BB * 1024), 256, 0, stream>>>(f3, p3, 16);
    wt_kernel<<<(CWD * NCO + 255) / 256, 256, 0, stream>>>(W, Wt);
    mb_prep_kernel<<<KK / 256, 256, 0, stream>>>(mb, mbTh, mbTl, mbn);
    lvl_gemm_kernel<<<dim3(7, 64, BB), 256, 0, stream>>>(p1, Wt, g1, 256,  4096, 0);
    lvl_gemm_kernel<<<dim3(7, 16, BB), 256, 0, stream>>>(p2, Wt, g2, 512,  1024, 256);
    lvl_gemm_kernel<<<dim3(7, 4,  BB), 256, 0, stream>>>(p3, Wt, g3, 1024, 256,  768);
    fuse_kernel<<<PP * BB / 4, 256, 0, stream>>>(g1, g2, g3, Wt, bias, th, tl, tn);
    dist_kernel<<<4096, 256, 0, stream>>>(th, tl, mbTh, mbTl, tn, mbn, part);
    score_kernel<<<PP * BB / 4, 256, 0, stream>>>(part, out);
}

// Round 11
// 1177.386 us; speedup vs baseline: 1.3346x; 1.2726x over previous
//
#include <hip/hip_runtime.h>
#include <cstddef>

#define BB   4
#define PP   4096      // 64*64
#define CWD  1794      // 1792 + 2 coord channels
#define NCO  448
#define KK   4096

typedef __attribute__((ext_vector_type(8))) short short8;
typedef __attribute__((ext_vector_type(4))) float f32x4;
typedef unsigned short u16;

static __device__ __forceinline__ u16 f2bf(float f) {
    unsigned int u = __float_as_uint(f);
    u += 0x7fffu + ((u >> 16) & 1u);    // round-to-nearest-even
    return (u16)(u >> 16);
}
static __device__ __forceinline__ float bf2f(u16 s) {
    return __uint_as_float(((unsigned int)s) << 16);
}
static __device__ __forceinline__ void ins3(float v, float& t0, float& t1, float& t2) {
    if (v < t0)      { t2 = t1; t1 = t0; t0 = v; }
    else if (v < t1) { t2 = t1; t1 = v; }
    else if (v < t2) { t2 = v; }
}

// ---------------- 3x3 avg pool, stride 1, pad 1, count_include_pad (sum/9) ----------------
__global__ void pool3_kernel(const float* __restrict__ in, float* __restrict__ out, int S) {
    int plane = blockIdx.y;
    int idx = blockIdx.x * 256 + threadIdx.x;
    if (idx >= S * S) return;
    int h = idx / S, w = idx % S;
    const float* p = in + (size_t)plane * S * S;
    float s = 0.f;
    for (int dh = -1; dh <= 1; ++dh) {
        int hh = h + dh;
        if (hh < 0 || hh >= S) continue;
        for (int dw = -1; dw <= 1; ++dw) {
            int ww = w + dw;
            if (ww < 0 || ww >= S) continue;
            s += p[hh * S + ww];
        }
    }
    out[(size_t)plane * S * S + idx] = s * (1.f / 9.f);
}

// ---------------- W[o][c] -> Wt[c][o] ----------------
__global__ void wt_kernel(const float* __restrict__ W, float* __restrict__ Wt) {
    int i = blockIdx.x * 256 + threadIdx.x;
    if (i >= CWD * NCO) return;
    int c = i / NCO, o = i % NCO;
    Wt[i] = W[(size_t)o * CWD + c];
}

// ---------------- mb prep: mbT_h/l[k][c] bf16 split + ||mb[:,k]||^2 (short8 writes) ----------
__global__ void mb_prep_kernel(const float* __restrict__ mb, u16* __restrict__ mbTh,
                               u16* __restrict__ mbTl, float* __restrict__ mbn) {
    int k = blockIdx.x * 256 + threadIdx.x;
    float s = 0.f;
    for (int c8 = 0; c8 < 56; ++c8) {
        short8 H, L;
        #pragma unroll
        for (int j = 0; j < 8; ++j) {
            float v = mb[(size_t)(c8 * 8 + j) * KK + k];   // coalesced along k
            s += v * v;
            u16 h = f2bf(v);
            H[j] = (short)h;
            L[j] = (short)f2bf(v - bf2f(h));
        }
        *(short8*)&mbTh[(size_t)k * NCO + c8 * 8] = H;
        *(short8*)&mbTl[(size_t)k * NCO + c8 * 8] = L;
    }
    mbn[k] = s;
}

// ---------------- per-level contribution GEMM: g[b,pix,o] = sum_c p[b,c,pix] * Wt[c0w+c][o] ---
__global__ __launch_bounds__(256) void lvl_gemm_kernel(
    const float* __restrict__ src, const float* __restrict__ Wt,
    float* __restrict__ g, int C, int PL, int c0w)
{
    __shared__ __align__(16) float A[64][64];
    __shared__ __align__(16) float Wl[64][64];

    int bz = blockIdx.z;
    int p0 = blockIdx.y * 64;
    int o0 = blockIdx.x * 64;
    int tid = threadIdx.x;
    int lane = tid & 63, grp = tid >> 6;
    int tx = tid & 15, ty = tid >> 4;
    float acc[4][4] = {};

    for (int c0 = 0; c0 < C; c0 += 64) {
        __syncthreads();
        #pragma unroll
        for (int i = 0; i < 16; ++i) {
            int cl = grp + 4 * i;
            Wl[cl][lane] = Wt[(size_t)(c0w + c0 + cl) * NCO + o0 + lane];
            A[cl][lane]  = src[((size_t)bz * C + c0 + cl) * PL + p0 + lane];
        }
        __syncthreads();
        #pragma unroll 8
        for (int c = 0; c < 64; ++c) {
            float4 a4 = *(const float4*)&A[c][tx * 4];
            float4 w4 = *(const float4*)&Wl[c][ty * 4];
            float av[4] = {a4.x, a4.y, a4.z, a4.w};
            float wv[4] = {w4.x, w4.y, w4.z, w4.w};
            #pragma unroll
            for (int i = 0; i < 4; ++i)
                #pragma unroll
                for (int j = 0; j < 4; ++j)
                    acc[i][j] = fmaf(av[i], wv[j], acc[i][j]);
        }
    }
    #pragma unroll
    for (int i = 0; i < 4; ++i) {
        float4 r;
        r.x = acc[i][0]; r.y = acc[i][1]; r.z = acc[i][2]; r.w = acc[i][3];
        *(float4*)&g[((size_t)bz * PL + p0 + tx * 4 + i) * NCO + o0 + ty * 4] = r;
    }
}

// ---------------- fuse: t = g1 + up2(g2) + up4(g3) + coords + bias; split bf16 + row norm -----
__global__ __launch_bounds__(256) void fuse_kernel(
    const float* __restrict__ g1, const float* __restrict__ g2, const float* __restrict__ g3,
    const float* __restrict__ Wt, const float* __restrict__ bias,
    u16* __restrict__ th, u16* __restrict__ tl, float* __restrict__ tn)
{
    int r = blockIdx.x * 4 + (threadIdx.x >> 6);
    int lane = threadIdx.x & 63;
    int b = r >> 12, p = r & 4095, h = p >> 6, w = p & 63;

    float s2h = 0.5f * h - 0.25f;  int h2a = (int)floorf(s2h); float f2h = s2h - h2a;
    int h2b = min(max(h2a + 1, 0), 31); h2a = min(max(h2a, 0), 31);
    float s2w = 0.5f * w - 0.25f;  int w2a = (int)floorf(s2w); float f2w = s2w - w2a;
    int w2b = min(max(w2a + 1, 0), 31); w2a = min(max(w2a, 0), 31);
    float s4h = 0.25f * h - 0.375f; int h4a = (int)floorf(s4h); float f4h = s4h - h4a;
    int h4b = min(max(h4a + 1, 0), 15); h4a = min(max(h4a, 0), 15);
    float s4w = 0.25f * w - 0.375f; int w4a = (int)floorf(s4w); float f4w = s4w - w4a;
    int w4b = min(max(w4a + 1, 0), 15); w4a = min(max(w4a, 0), 15);

    float c2aa = (1.f - f2h) * (1.f - f2w), c2ab = (1.f - f2h) * f2w;
    float c2ba = f2h * (1.f - f2w),         c2bb = f2h * f2w;
    float c4aa = (1.f - f4h) * (1.f - f4w), c4ab = (1.f - f4h) * f4w;
    float c4ba = f4h * (1.f - f4w),         c4bb = f4h * f4w;

    const float* G1 = g1 + (size_t)r * NCO;
    const float* G2 = g2 + (size_t)b * 1024 * NCO;
    const float* G3 = g3 + (size_t)b * 256 * NCO;
    size_t i2aa = (size_t)(h2a * 32 + w2a) * NCO, i2ab = (size_t)(h2a * 32 + w2b) * NCO;
    size_t i2ba = (size_t)(h2b * 32 + w2a) * NCO, i2bb = (size_t)(h2b * 32 + w2b) * NCO;
    size_t i4aa = (size_t)(h4a * 16 + w4a) * NCO, i4ab = (size_t)(h4a * 16 + w4b) * NCO;
    size_t i4ba = (size_t)(h4b * 16 + w4a) * NCO, i4bb = (size_t)(h4b * 16 + w4b) * NCO;

    float xx = (float)h * (2.f / 63.f) - 1.f;
    float yy = (float)w * (2.f / 63.f) - 1.f;

    float s = 0.f;
    #pragma unroll
    for (int j = 0; j < 7; ++j) {
        int c = lane + 64 * j;
        float v = G1[c]
            + c2aa * G2[i2aa + c] + c2ab * G2[i2ab + c]
            + c2ba * G2[i2ba + c] + c2bb * G2[i2bb + c]
            + c4aa * G3[i4aa + c] + c4ab * G3[i4ab + c]
            + c4ba * G3[i4ba + c] + c4bb * G3[i4bb + c]
            + xx * Wt[(size_t)1792 * NCO + c] + yy * Wt[(size_t)1793 * NCO + c] + bias[c];
        u16 hi = f2bf(v);
        th[(size_t)r * NCO + c] = hi;
        tl[(size_t)r * NCO + c] = f2bf(v - bf2f(hi));
        s += v * v;
    }
    #pragma unroll
    for (int off = 32; off > 0; off >>= 1) s += __shfl_down(s, off);
    if (lane == 0) tn[r] = s;
}

// ---------------- dist: 128x128 MFMA GEMM, A+B reg-staged into swizzled LDS ----------------
// m97-style 2-barrier loop. LDS: 4 linear arrays [128 rows][8 chunks of 16B]; physical chunk
// p of a row holds logical chunk p^(row&7) (both-sides XOR swizzle: pre-swizzled global
// SOURCE offsets + swizzled ds_read). Staging = plain uint4 load -> ds_write (validated
// mechanism, rounds 4/7); no cross-iteration prefetch regs -> no spill (round-7 root cause).
// th/tl/mbTh/mbTl contiguous from th at element offsets 0 / 7340032 / 14680064 / 16515072.
__global__ __launch_bounds__(256, 2) void dist_kernel(
    const u16* __restrict__ th, const float* __restrict__ tn,
    const float* __restrict__ mbn, float* __restrict__ part)
{
    __shared__ __align__(16) u16 LDSB[4 * 128 * 64];   // Ah | Al | Bh | Bl, 16 KB each
    __shared__ float MRG[128][2][3];

    int bid = blockIdx.x;
    int swz = (bid & 7) * 512 + (bid >> 3);     // XCD swizzle (4096 % 8 == 0: bijective)
    int mt = swz >> 5, nt = swz & 31;
    int r0 = mt * 128, n0 = nt * 128;
    int tid = threadIdx.x;
    int lane = tid & 63, wv = tid >> 6;
    int wm = wv >> 1, wn = wv & 1;
    int l15 = lane & 15, l4 = lane >> 4;

    // per-lane pre-swizzled global byte offsets (from th) for this thread's 16 chunks at k0=0.
    // chunk id I: arr = I>>10 (0:th 1:tl 2:mbTh 3:mbTl), row = (I&1023)>>3, phys = I&7,
    // logical c = phys ^ (row&7)  -> source element = base(arr) + (rbase+row)*448 + c*8
    unsigned int off[16];
    #pragma unroll
    for (int i = 0; i < 16; ++i) {
        int I = (i * 4 + wv) * 64 + lane;
        int arr = I >> 10;
        int J = I & 1023;
        int row = J >> 3;
        int c = (J & 7) ^ (row & 7);
        unsigned int ebase = (arr == 0) ? 0u : (arr == 1) ? 7340032u
                           : (arr == 2) ? 14680064u : 16515072u;
        unsigned int rbase = (arr < 2) ? (unsigned int)r0 : (unsigned int)n0;
        off[i] = (ebase + (rbase + (unsigned int)row) * 448u + (unsigned int)c * 8u) * 2u;
    }

    f32x4 acc[4][4];
    #pragma unroll
    for (int i = 0; i < 4; ++i)
        #pragma unroll
        for (int j = 0; j < 4; ++j) acc[i][j] = (f32x4){0.f, 0.f, 0.f, 0.f};

    const char* gbase = (const char*)th;
    char* lbase = (char*)&LDSB[0];

    for (int t7 = 0; t7 < 7; ++t7) {
        // stage: each thread copies its 16 chunks (load -> ds_write, transient regs only)
        #pragma unroll
        for (int i = 0; i < 16; ++i) {
            uint4 v = *(const uint4*)(gbase + off[i]);
            *(uint4*)(lbase + ((i * 4 + wv) * 64 + lane) * 16) = v;
            off[i] += 128;                     // next K-step: +64 u16
        }
        __syncthreads();                       // staging visible to all waves

        #pragma unroll
        for (int ks = 0; ks < 2; ++ks) {
            int cl = ks * 4 + l4;              // logical chunk 0..7
            int psw = cl ^ (l15 & 7);          // physical chunk (row&7 == l15&7 for all frags)
            short8 ah[4], al[4];
            #pragma unroll
            for (int i = 0; i < 4; ++i) {
                int row = wm * 64 + i * 16 + l15;
                ah[i] = *(const short8*)&LDSB[           row * 64 + psw * 8];
                al[i] = *(const short8*)&LDSB[ 8192 +    row * 64 + psw * 8];
            }
            #pragma unroll
            for (int j = 0; j < 4; ++j) {
                int brow = wn * 64 + j * 16 + l15;
                short8 bh = *(const short8*)&LDSB[16384 + brow * 64 + psw * 8];
                short8 bl = *(const short8*)&LDSB[24576 + brow * 64 + psw * 8];
                #pragma unroll
                for (int i = 0; i < 4; ++i) {
                    acc[i][j] = __builtin_amdgcn_mfma_f32_16x16x32_bf16(ah[i], bh, acc[i][j], 0, 0, 0);
                    acc[i][j] = __builtin_amdgcn_mfma_f32_16x16x32_bf16(ah[i], bl, acc[i][j], 0, 0, 0);
                    acc[i][j] = __builtin_amdgcn_mfma_f32_16x16x32_bf16(al[i], bh, acc[i][j], 0, 0, 0);
                }
            }
        }
        __syncthreads();                       // reads done before next stage overwrites
    }

    // epilogue: d2 = tn + mbn - 2*dot; per-row top-3 over this block's 128 cols (validated r4/r7)
    float nbv[4];
    #pragma unroll
    for (int j = 0; j < 4; ++j) nbv[j] = mbn[n0 + wn * 64 + j * 16 + l15];

    #pragma unroll
    for (int i = 0; i < 4; ++i) {
        #pragma unroll
        for (int rr = 0; rr < 4; ++rr) {
            int mloc = wm * 64 + i * 16 + l4 * 4 + rr;
            float tv = tn[r0 + mloc];
            float t0 = 3.4e38f, t1 = 3.4e38f, t2 = 3.4e38f;
            #pragma unroll
            for (int j = 0; j < 4; ++j)
                ins3(tv + nbv[j] - 2.f * acc[i][j][rr], t0, t1, t2);
            #pragma unroll
            for (int mask = 1; mask <= 8; mask <<= 1) {   // butterfly over l15 bits
                float o0 = __shfl_xor(t0, mask);
                float o1 = __shfl_xor(t1, mask);
                float o2 = __shfl_xor(t2, mask);
                ins3(o0, t0, t1, t2); ins3(o1, t0, t1, t2); ins3(o2, t0, t1, t2);
            }
            if (l15 == 0) {
                MRG[mloc][wn][0] = t0; MRG[mloc][wn][1] = t1; MRG[mloc][wn][2] = t2;
            }
        }
    }
    __syncthreads();
    if (tid < 128) {
        float t0 = MRG[tid][0][0], t1 = MRG[tid][0][1], t2 = MRG[tid][0][2];
        ins3(MRG[tid][1][0], t0, t1, t2);
        ins3(MRG[tid][1][1], t0, t1, t2);
        ins3(MRG[tid][1][2], t0, t1, t2);
        size_t o = (size_t)(r0 + tid) * 96 + nt * 3;
        part[o] = t0; part[o + 1] = t1; part[o + 2] = t2;
    }
}

// ---------------- final merge: top-3 of 32 partial triples + softmin score ----------------
__global__ void score_kernel(const float* __restrict__ part, float* __restrict__ out) {
    int r = blockIdx.x * 4 + (threadIdx.x >> 6);
    int lane = threadIdx.x & 63;
    float t0 = 3.4e38f, t1 = 3.4e38f, t2 = 3.4e38f;
    ins3(part[(size_t)r * 96 + lane], t0, t1, t2);
    float v1 = (lane < 32) ? part[(size_t)r * 96 + 64 + lane] : 3.4e38f;
    ins3(v1, t0, t1, t2);
    #pragma unroll
    for (int mask = 1; mask <= 32; mask <<= 1) {
        float o0 = __shfl_xor(t0, mask);
        float o1 = __shfl_xor(t1, mask);
        float o2 = __shfl_xor(t2, mask);
        ins3(o0, t0, t1, t2); ins3(o1, t0, t1, t2); ins3(o2, t0, t1, t2);
    }
    if (lane == 0) {
        float d1 = sqrtf(fmaxf(t0, 1e-12f));
        float d2 = sqrtf(fmaxf(t1, 1e-12f));
        float d3 = sqrtf(fmaxf(t2, 1e-12f));
        float e2 = expf(d1 - d2), e3 = expf(d1 - d3);   // both <= 1, stable
        out[r] = d1 / (1.f + e2 + e3);
    }
}

extern "C" void kernel_launch(void* const* d_in, const int* in_sizes, int n_in,
                              void* d_out, int out_size, void* d_ws, size_t ws_size,
                              hipStream_t stream) {
    (void)in_sizes; (void)n_in; (void)out_size; (void)ws_size;
    const float* f1   = (const float*)d_in[0];
    const float* f2   = (const float*)d_in[1];
    const float* f3   = (const float*)d_in[2];
    const float* W    = (const float*)d_in[3];
    const float* bias = (const float*)d_in[4];
    const float* mb   = (const float*)d_in[5];
    float* out = (float*)d_out;

    // workspace: 94.15 MB total (same layout as passing rounds 4/7)
    float* p1  = (float*)d_ws;                       // 4,194,304 f
    float* p2  = p1  + (size_t)4194304;              // 2,097,152 f
    float* p3  = p2  + (size_t)2097152;              // 1,048,576 f
    float* Wt  = p3  + (size_t)1048576;              //   803,712 f
    float* g1  = Wt  + (size_t)803712;               // 7,340,032 f
    float* tn  = g1  + (size_t)7340032;              //    16,384 f
    float* mbn = tn  + (size_t)16384;                //     4,096 f
    u16* th    = (u16*)(mbn + 4096);                 // 7,340,032 u16 (16B-aligned)
    u16* tl    = th   + (size_t)7340032;             // 7,340,032 u16
    u16* mbTh  = tl   + (size_t)7340032;             // 1,835,008 u16
    u16* mbTl  = mbTh + (size_t)1835008;             // 1,835,008 u16  (contiguous with th!)
    // aliases into dead regions (stream order guarantees safety):
    float* g2   = p1;                                // 1,835,008 f (p1 dead after L1 GEMM)
    float* part = p1 + (size_t)1835008;              // 1,572,864 f (written by dist, after fuse)
    float* g3   = p2;                                //   458,752 f (p2 dead after L2 GEMM)

    pool3_kernel<<<dim3(16, BB * 256),  256, 0, stream>>>(f1, p1, 64);
    pool3_kernel<<<dim3(4,  BB * 512),  256, 0, stream>>>(f2, p2, 32);
    pool3_kernel<<<dim3(1,  BB * 1024), 256, 0, stream>>>(f3, p3, 16);
    wt_kernel<<<(CWD * NCO + 255) / 256, 256, 0, stream>>>(W, Wt);
    mb_prep_kernel<<<KK / 256, 256, 0, stream>>>(mb, mbTh, mbTl, mbn);
    lvl_gemm_kernel<<<dim3(7, 64, BB), 256, 0, stream>>>(p1, Wt, g1, 256,  4096, 0);
    lvl_gemm_kernel<<<dim3(7, 16, BB), 256, 0, stream>>>(p2, Wt, g2, 512,  1024, 256);
    lvl_gemm_kernel<<<dim3(7, 4,  BB), 256, 0, stream>>>(p3, Wt, g3, 1024, 256,  768);
    fuse_kernel<<<PP * BB / 4, 256, 0, stream>>>(g1, g2, g3, Wt, bias, th, tl, tn);
    dist_kernel<<<4096, 256, 0, stream>>>(th, tn, mbn, part);
    score_kernel<<<PP * BB / 4, 256, 0, stream>>>(part, out);
}